// Round 1
// baseline (1286.949 us; speedup 1.0000x reference)
//
#include <hip/hip_runtime.h>
#include <hip/hip_bf16.h>

typedef __attribute__((ext_vector_type(8))) __bf16 bf16x8;
typedef __attribute__((ext_vector_type(4))) float f32x4;

#define M_TOT 8192        // Bsz*S = 4*2048
#define IN_DIM 4096
#define R_BLK 256
#define K_CNT 128
#define MT 256            // rows per workgroup
#define NTHR 512          // 8 waves
#define MTILES (M_TOT / MT)      // 32
#define NWG (MTILES * R_BLK)     // 8192

__device__ __forceinline__ __bf16 f2bf(float f) { return (__bf16)f; }

// f32 -> bf16 bulk convert, 8 elements/thread
__global__ void cvt_f32_bf16(const float* __restrict__ in, __bf16* __restrict__ out, int n8) {
  int i = blockIdx.x * blockDim.x + threadIdx.x;
  if (i >= n8) return;
  const f32x4* p = (const f32x4*)(in + (size_t)i * 8);
  f32x4 a = p[0], b = p[1];
  bf16x8 o;
  o[0] = f2bf(a[0]); o[1] = f2bf(a[1]); o[2] = f2bf(a[2]); o[3] = f2bf(a[3]);
  o[4] = f2bf(b[0]); o[5] = f2bf(b[1]); o[6] = f2bf(b[2]); o[7] = f2bf(b[3]);
  *(bf16x8*)(out + (size_t)i * 8) = o;
}

// One WG = (mtile of 256 rows, r). 8 waves, each wave owns 32 rows x 16 cols.
// K-loop: 4 gathered 16-col blocks per iter (K=64), mfma_f32_16x16x32_bf16.
template <bool PRE>
__launch_bounds__(NTHR, 4)
__global__ void bsmm(const float* __restrict__ x32, const __bf16* __restrict__ xbf,
                     const float* __restrict__ v32, const __bf16* __restrict__ vbf,
                     const int* __restrict__ cols, float* __restrict__ out) {
  // x tile: [row][64 bf16] = 128 B/row, XOR-swizzled 16B slots (conflict-free b128)
  __shared__ ushort lx[MT * 64];          // 32 KB
  // V tile: [o][4 blocks * 16 i] = 128 B/row, same swizzle
  __shared__ ushort lv[16 * 64];          // 2 KB
  __shared__ int lcol[K_CNT];

  // XCD-aware swizzle: each XCD gets contiguous logical range -> x-tile stays in its L2
  int b = blockIdx.x;
  int logical = (b & 7) * (NWG >> 3) + (b >> 3);
  int mt = logical >> 8;          // 0..31
  int r  = logical & 255;
  int m0 = mt * MT;

  int tid = threadIdx.x;
  if (tid < K_CNT) lcol[tid] = cols[r * K_CNT + tid];

  int lane = tid & 63, wave = tid >> 6;
  int l15 = lane & 15, j4 = lane >> 4;

  f32x4 acc0 = {0.f, 0.f, 0.f, 0.f};
  f32x4 acc1 = {0.f, 0.f, 0.f, 0.f};

  for (int t = 0; t < K_CNT / 4; ++t) {
    __syncthreads();   // also covers lcol on t==0; protects LDS from prev compute
    // ---- stage x: 256 rows x 64 cols (4 gathered blocks), 4 x 16B per thread
#pragma unroll
    for (int s = 0; s < 4; ++s) {
      int ch = s * NTHR + tid;        // 0..2047 chunks of 8 bf16
      int row = ch >> 3, s8 = ch & 7; // 8 slots (16B) per row
      int cb = lcol[t * 4 + (s8 >> 1)];
      size_t goff = (size_t)(m0 + row) * IN_DIM + cb * 16 + (s8 & 1) * 8;
      bf16x8 val;
      if (PRE) {
        val = *(const bf16x8*)(xbf + goff);
      } else {
        const f32x4* p = (const f32x4*)(x32 + goff);
        f32x4 a = p[0], bq = p[1];
        val[0] = f2bf(a[0]);  val[1] = f2bf(a[1]);  val[2] = f2bf(a[2]);  val[3] = f2bf(a[3]);
        val[4] = f2bf(bq[0]); val[5] = f2bf(bq[1]); val[6] = f2bf(bq[2]); val[7] = f2bf(bq[3]);
      }
      int byteo = row * 128 + ((s8 * 16) ^ ((row & 7) << 4));
      *(bf16x8*)((char*)lx + byteo) = val;
    }
    // ---- stage V: 4 blocks x 16o x 16i, threads 0..127, 16B each
    if (tid < 128) {
      int kb = tid >> 5, o = (tid >> 1) & 15, ih = tid & 1;
      size_t goff = ((size_t)r * K_CNT + t * 4 + kb) * 256 + o * 16 + ih * 8;
      bf16x8 val;
      if (PRE) {
        val = *(const bf16x8*)(vbf + goff);
      } else {
        const f32x4* p = (const f32x4*)(v32 + goff);
        f32x4 a = p[0], bq = p[1];
        val[0] = f2bf(a[0]);  val[1] = f2bf(a[1]);  val[2] = f2bf(a[2]);  val[3] = f2bf(a[3]);
        val[4] = f2bf(bq[0]); val[5] = f2bf(bq[1]); val[6] = f2bf(bq[2]); val[7] = f2bf(bq[3]);
      }
      int byteo = o * 128 + (((kb * 2 + ih) * 16) ^ ((o & 7) << 4));
      *(bf16x8*)((char*)lv + byteo) = val;
    }
    __syncthreads();
    // ---- compute: per wave 2 m-frags x 2 K32-steps = 4 mfma
#pragma unroll
    for (int ks = 0; ks < 2; ++ks) {
      int colb = ks * 64 + j4 * 16;   // byte offset of this lane's 16B within a 128B row
      bf16x8 bfrg = *(const bf16x8*)((char*)lv + l15 * 128 + (colb ^ ((l15 & 7) << 4)));
      int rowA0 = wave * 32 + l15;
      bf16x8 a0 = *(const bf16x8*)((char*)lx + rowA0 * 128 + (colb ^ ((rowA0 & 7) << 4)));
      int rowA1 = rowA0 + 16;
      bf16x8 a1 = *(const bf16x8*)((char*)lx + rowA1 * 128 + (colb ^ ((rowA1 & 7) << 4)));
      acc0 = __builtin_amdgcn_mfma_f32_16x16x32_bf16(a0, bfrg, acc0, 0, 0, 0);
      acc1 = __builtin_amdgcn_mfma_f32_16x16x32_bf16(a1, bfrg, acc1, 0, 0, 0);
    }
  }
  // ---- epilogue: D layout col=lane&15, row=(lane>>4)*4+q
#pragma unroll
  for (int q = 0; q < 4; ++q) {
    int row0 = m0 + wave * 32 + j4 * 4 + q;
    out[(size_t)row0 * 4096 + r * 16 + l15] = acc0[q];
    out[(size_t)(row0 + 16) * 4096 + r * 16 + l15] = acc1[q];
  }
}

extern "C" void kernel_launch(void* const* d_in, const int* in_sizes, int n_in,
                              void* d_out, int out_size, void* d_ws, size_t ws_size,
                              hipStream_t stream) {
  const float* x32 = (const float*)d_in[0];
  const float* v32 = (const float*)d_in[1];
  const int*   cols = (const int*)d_in[2];
  float* out = (float*)d_out;

  const size_t xel = (size_t)M_TOT * IN_DIM;        // 33,554,432
  const size_t vel = (size_t)R_BLK * K_CNT * 256;   // 8,388,608
  const size_t need = xel * 2 + vel * 2;            // 83,886,080 B

  if (ws_size >= need) {
    __bf16* xbf = (__bf16*)d_ws;
    __bf16* vbf = xbf + xel;
    cvt_f32_bf16<<<(int)(xel / 8 / 256), 256, 0, stream>>>(x32, xbf, (int)(xel / 8));
    cvt_f32_bf16<<<(int)(vel / 8 / 256), 256, 0, stream>>>(v32, vbf, (int)(vel / 8));
    bsmm<true><<<NWG, NTHR, 0, stream>>>(x32, xbf, v32, vbf, cols, out);
  } else {
    bsmm<false><<<NWG, NTHR, 0, stream>>>(x32, nullptr, v32, nullptr, cols, out);
  }
}

// Round 2
// 649.662 us; speedup vs baseline: 1.9810x; 1.9810x over previous
//
#include <hip/hip_runtime.h>
#include <hip/hip_bf16.h>

typedef __attribute__((ext_vector_type(8))) __bf16 bf16x8;
typedef __attribute__((ext_vector_type(4))) float f32x4;

#define M_TOT 8192        // Bsz*S
#define IN_DIM 4096
#define R_BLK 256
#define K_CNT 128

// GEMM tile config (m97-style 128x128, BK=64, 4 waves)
#define BM 128
#define BN 128
#define BK 64
#define GT 256

__device__ __forceinline__ __bf16 f2bf(float f) { return (__bf16)f; }

// ---------------- f32 -> bf16 bulk convert, 8 elem/thread ----------------
__global__ void cvt_f32_bf16(const float* __restrict__ in, __bf16* __restrict__ out, int n8) {
  int i = blockIdx.x * blockDim.x + threadIdx.x;
  if (i >= n8) return;
  const f32x4* p = (const f32x4*)(in + (size_t)i * 8);
  f32x4 a = p[0], b = p[1];
  bf16x8 o;
  o[0] = f2bf(a[0]); o[1] = f2bf(a[1]); o[2] = f2bf(a[2]); o[3] = f2bf(a[3]);
  o[4] = f2bf(b[0]); o[5] = f2bf(b[1]); o[6] = f2bf(b[2]); o[7] = f2bf(b[3]);
  *(bf16x8*)(out + (size_t)i * 8) = o;
}

// ---------------- build W^T in f32: Wf[n=r*16+o][c*16+i] = sum_k V ----------------
// One WG per r; thread (o,i) owns W-slots {(r*16+o, c*16+i) : c} -> no atomics needed.
__global__ __launch_bounds__(256) void wbuild(const float* __restrict__ v32,
                                              const int* __restrict__ cols,
                                              float* __restrict__ Wf) {
  int r = blockIdx.x;
  __shared__ int lcol[K_CNT];
  int tid = threadIdx.x;
  if (tid < K_CNT) lcol[tid] = cols[r * K_CNT + tid];
  __syncthreads();
  int o = tid >> 4, i = tid & 15;
  float* wrow = Wf + (size_t)(r * 16 + o) * IN_DIM + i;
  // zero own slots (ws is poisoned 0xAA each call)
  for (int c = 0; c < 256; ++c) wrow[c * 16] = 0.f;
  const float* vp = v32 + (size_t)r * K_CNT * 256 + o * 16 + i;
  for (int k = 0; k < K_CNT; ++k) {
    wrow[lcol[k] * 16] += vp[(size_t)k * 256];
  }
}

// ---------------- dense GEMM: out[8192][4096] = A[8192][4096] * Wt^T ----------------
// A row-major [M][K] bf16, Wt row-major [N][K] bf16. global_load_lds w=16,
// XOR-swizzled LDS (conflict-free ds_read_b128), mfma_f32_16x16x32_bf16.
__global__ __launch_bounds__(GT) void gemm_bf16(const __bf16* __restrict__ A,
                                                const __bf16* __restrict__ Wt,
                                                float* __restrict__ out) {
  __shared__ ushort lA[BM * BK];   // 16 KB, 128 B rows
  __shared__ ushort lB[BN * BK];   // 16 KB

  int b = blockIdx.x;
  int logical = (b & 7) * 256 + (b >> 3);   // XCD swizzle, 2048 WGs (%8==0)
  int mt = logical & 63, nt = logical >> 6; // per XCD: 4 n-panels (4MB Wt) hot in L2
  int m0 = mt * BM, n0 = nt * BN;

  int tid = threadIdx.x, lane = tid & 63, wave = tid >> 6;
  int l15 = lane & 15, j4 = lane >> 4;
  int wr = wave >> 1, wc = wave & 1;

  // staging geometry: chunk = 1KB = 8 rows; lane -> (row-in-chunk, 16B slot)
  int rowc = lane >> 3, slot = lane & 7;
  int sblk = slot ^ rowc;   // pre-swizzled global source block (involution)

  f32x4 acc[4][4];
#pragma unroll
  for (int ai = 0; ai < 4; ++ai)
#pragma unroll
    for (int bj = 0; bj < 4; ++bj) acc[ai][bj] = (f32x4){0.f, 0.f, 0.f, 0.f};

  for (int t = 0; t < IN_DIM / BK; ++t) {
    __syncthreads();
#pragma unroll
    for (int is = 0; is < 4; ++is) {
      int chunk = is * 4 + wave;        // 0..15
      int row = chunk * 8 + rowc;       // tile row
      const __bf16* ga = A + (size_t)(m0 + row) * IN_DIM + t * BK + sblk * 8;
      __builtin_amdgcn_global_load_lds(
          (const __attribute__((address_space(1))) void*)ga,
          (__attribute__((address_space(3))) void*)((char*)lA + chunk * 1024), 16, 0, 0);
      const __bf16* gb = Wt + (size_t)(n0 + row) * IN_DIM + t * BK + sblk * 8;
      __builtin_amdgcn_global_load_lds(
          (const __attribute__((address_space(1))) void*)gb,
          (__attribute__((address_space(3))) void*)((char*)lB + chunk * 1024), 16, 0, 0);
    }
    __syncthreads();   // compiler drains vmcnt(0) here (m97 structure)
#pragma unroll
    for (int ks = 0; ks < 2; ++ks) {
      int cb = ks * 64 + j4 * 16;   // byte offset of this lane's 16B slot
      bf16x8 bf[4], af[4];
#pragma unroll
      for (int bj = 0; bj < 4; ++bj) {
        int rn = wc * 64 + bj * 16 + l15;
        bf[bj] = *(const bf16x8*)((char*)lB + rn * 128 + (cb ^ ((rn & 7) << 4)));
      }
#pragma unroll
      for (int ai = 0; ai < 4; ++ai) {
        int rm = wr * 64 + ai * 16 + l15;
        af[ai] = *(const bf16x8*)((char*)lA + rm * 128 + (cb ^ ((rm & 7) << 4)));
      }
#pragma unroll
      for (int ai = 0; ai < 4; ++ai)
#pragma unroll
        for (int bj = 0; bj < 4; ++bj)
          acc[ai][bj] = __builtin_amdgcn_mfma_f32_16x16x32_bf16(af[ai], bf[bj], acc[ai][bj], 0, 0, 0);
    }
  }
  // epilogue: D layout col=lane&15, row=(lane>>4)*4+q
#pragma unroll
  for (int ai = 0; ai < 4; ++ai)
#pragma unroll
    for (int bj = 0; bj < 4; ++bj)
#pragma unroll
      for (int q = 0; q < 4; ++q) {
        int m = m0 + wr * 64 + ai * 16 + j4 * 4 + q;
        int n = n0 + wc * 64 + bj * 16 + l15;
        out[(size_t)m * 4096 + n] = acc[ai][bj][q];
      }
}

// ---------------- fallback (round-1 kernel, f32 inline-convert path) ----------------
#define MT 256
#define NTHR 512
#define NWG ((M_TOT / MT) * R_BLK)

__launch_bounds__(NTHR, 4)
__global__ void bsmm_f32(const float* __restrict__ x32, const float* __restrict__ v32,
                         const int* __restrict__ cols, float* __restrict__ out) {
  __shared__ ushort lx[MT * 64];
  __shared__ ushort lv[16 * 64];
  __shared__ int lcol[K_CNT];

  int b = blockIdx.x;
  int logical = (b & 7) * (NWG >> 3) + (b >> 3);
  int mt = logical >> 8;
  int r  = logical & 255;
  int m0 = mt * MT;

  int tid = threadIdx.x;
  if (tid < K_CNT) lcol[tid] = cols[r * K_CNT + tid];

  int lane = tid & 63, wave = tid >> 6;
  int l15 = lane & 15, j4 = lane >> 4;

  f32x4 acc0 = {0.f, 0.f, 0.f, 0.f};
  f32x4 acc1 = {0.f, 0.f, 0.f, 0.f};

  for (int t = 0; t < K_CNT / 4; ++t) {
    __syncthreads();
#pragma unroll
    for (int s = 0; s < 4; ++s) {
      int ch = s * NTHR + tid;
      int row = ch >> 3, s8 = ch & 7;
      int cb = lcol[t * 4 + (s8 >> 1)];
      size_t goff = (size_t)(m0 + row) * IN_DIM + cb * 16 + (s8 & 1) * 8;
      const f32x4* p = (const f32x4*)(x32 + goff);
      f32x4 a = p[0], bq = p[1];
      bf16x8 val;
      val[0] = f2bf(a[0]);  val[1] = f2bf(a[1]);  val[2] = f2bf(a[2]);  val[3] = f2bf(a[3]);
      val[4] = f2bf(bq[0]); val[5] = f2bf(bq[1]); val[6] = f2bf(bq[2]); val[7] = f2bf(bq[3]);
      int byteo = row * 128 + ((s8 * 16) ^ ((row & 7) << 4));
      *(bf16x8*)((char*)lx + byteo) = val;
    }
    if (tid < 128) {
      int kb = tid >> 5, o = (tid >> 1) & 15, ih = tid & 1;
      size_t goff = ((size_t)r * K_CNT + t * 4 + kb) * 256 + o * 16 + ih * 8;
      const f32x4* p = (const f32x4*)(v32 + goff);
      f32x4 a = p[0], bq = p[1];
      bf16x8 val;
      val[0] = f2bf(a[0]);  val[1] = f2bf(a[1]);  val[2] = f2bf(a[2]);  val[3] = f2bf(a[3]);
      val[4] = f2bf(bq[0]); val[5] = f2bf(bq[1]); val[6] = f2bf(bq[2]); val[7] = f2bf(bq[3]);
      int byteo = o * 128 + (((kb * 2 + ih) * 16) ^ ((o & 7) << 4));
      *(bf16x8*)((char*)lv + byteo) = val;
    }
    __syncthreads();
#pragma unroll
    for (int ks = 0; ks < 2; ++ks) {
      int colb = ks * 64 + j4 * 16;
      bf16x8 bfrg = *(const bf16x8*)((char*)lv + l15 * 128 + (colb ^ ((l15 & 7) << 4)));
      int rowA0 = wave * 32 + l15;
      bf16x8 a0 = *(const bf16x8*)((char*)lx + rowA0 * 128 + (colb ^ ((rowA0 & 7) << 4)));
      int rowA1 = rowA0 + 16;
      bf16x8 a1 = *(const bf16x8*)((char*)lx + rowA1 * 128 + (colb ^ ((rowA1 & 7) << 4)));
      acc0 = __builtin_amdgcn_mfma_f32_16x16x32_bf16(a0, bfrg, acc0, 0, 0, 0);
      acc1 = __builtin_amdgcn_mfma_f32_16x16x32_bf16(a1, bfrg, acc1, 0, 0, 0);
    }
  }
#pragma unroll
  for (int q = 0; q < 4; ++q) {
    int row0 = m0 + wave * 32 + j4 * 4 + q;
    out[(size_t)row0 * 4096 + r * 16 + l15] = acc0[q];
    out[(size_t)(row0 + 16) * 4096 + r * 16 + l15] = acc1[q];
  }
}

extern "C" void kernel_launch(void* const* d_in, const int* in_sizes, int n_in,
                              void* d_out, int out_size, void* d_ws, size_t ws_size,
                              hipStream_t stream) {
  const float* x32 = (const float*)d_in[0];
  const float* v32 = (const float*)d_in[1];
  const int*   cols = (const int*)d_in[2];
  float* out = (float*)d_out;

  const size_t xel = (size_t)M_TOT * IN_DIM;       // 33.5M
  const size_t wel = (size_t)IN_DIM * IN_DIM;      // 16.8M
  const size_t need = xel * 2 + wel * 4 + wel * 2; // xbf + Wf + Wbf = 160 MB

  if (ws_size >= need) {
    __bf16* xbf = (__bf16*)d_ws;
    float*  Wf  = (float*)((char*)d_ws + xel * 2);
    __bf16* Wbf = (__bf16*)((char*)d_ws + xel * 2 + wel * 4);
    cvt_f32_bf16<<<(int)(xel / 8 / 256), 256, 0, stream>>>(x32, xbf, (int)(xel / 8));
    wbuild<<<R_BLK, 256, 0, stream>>>(v32, cols, Wf);
    cvt_f32_bf16<<<(int)(wel / 8 / 256), 256, 0, stream>>>(Wf, Wbf, (int)(wel / 8));
    gemm_bf16<<<(M_TOT / BM) * (IN_DIM / BN), GT, 0, stream>>>(xbf, Wbf, out);
  } else {
    bsmm_f32<<<NWG, NTHR, 0, stream>>>(x32, v32, cols, out);
  }
}